// Round 1
// baseline (1728.304 us; speedup 1.0000x reference)
//
#include <hip/hip_runtime.h>

// Problem constants (from reference)
constexpr int NN   = 50000;            // nodes
constexpr int NE   = 800000;           // edges (before self-loops)
constexpr int NET  = NE + NN;          // edges incl. self-loops
constexpr int NG   = 512;              // graphs
constexpr int NLAT = 64;               // latent dim
constexpr float SLOPE = 0.2f;          // leaky relu slope

// ---- order-preserving float<->uint encoding so memset(0) == -inf ----
__device__ __forceinline__ unsigned fenc(float f) {
  unsigned u = __float_as_uint(f);
  return (u & 0x80000000u) ? ~u : (u | 0x80000000u);
}
__device__ __forceinline__ float fdec(unsigned u) {
  return (u & 0x80000000u) ? __uint_as_float(u & 0x7fffffffu)
                           : __uint_as_float(~u);
}

// C[n, j] = sum_k X[n,k] * W[k,j]; K fixed at 128. CN = output cols (128 or 32).
template <int CN>
__global__ void gemm_k128(const float* __restrict__ X, const float* __restrict__ W,
                          float* __restrict__ Hout) {
  constexpr int RPI = 256 / CN;   // rows covered per "column sweep"
  constexpr int R   = RPI * 4;    // rows per block (each thread: 4 accumulators)
  __shared__ float xs[R][128];
  const int col  = threadIdx.x % CN;
  const int rsub = threadIdx.x / CN;
  const int row0 = blockIdx.x * R;
  for (int i = threadIdx.x; i < R * 128; i += 256) {
    int r = i >> 7, k = i & 127;
    int gr = row0 + r;
    xs[r][k] = (gr < NN) ? X[gr * 128 + k] : 0.0f;
  }
  __syncthreads();
  float acc[4] = {0.f, 0.f, 0.f, 0.f};
  for (int k = 0; k < 128; ++k) {
    float w = W[k * CN + col];
#pragma unroll
    for (int rr = 0; rr < 4; ++rr)
      acc[rr] = fmaf(xs[rsub + rr * RPI][k], w, acc[rr]);
  }
#pragma unroll
  for (int rr = 0; rr < 4; ++rr) {
    int gr = row0 + rsub + rr * RPI;
    if (gr < NN) Hout[gr * CN + col] = acc[rr];
  }
}

// al_src[n,h] = sum_c h[n,h,c]*a_src[h,c]; F = H*32 (128 or 32).
template <int F>
__global__ void attn_coef(const float* __restrict__ Hf, const float* __restrict__ a_s,
                          const float* __restrict__ a_d, float* __restrict__ al_s,
                          float* __restrict__ al_d) {
  constexpr int NODES = 256 / F;
  const int t = threadIdx.x % F;
  const int node = blockIdx.x * NODES + threadIdx.x / F;
  if (node >= NN) return;
  float v  = Hf[node * F + t];
  float ps = v * a_s[t];
  float pd = v * a_d[t];
#pragma unroll
  for (int off = 16; off >= 1; off >>= 1) {  // reduce within aligned 32-lane group
    ps += __shfl_xor(ps, off, 64);
    pd += __shfl_xor(pd, off, 64);
  }
  if ((t & 31) == 0) {
    al_s[node * (F / 32) + (t >> 5)] = ps;
    al_d[node * (F / 32) + (t >> 5)] = pd;
  }
}

__device__ __forceinline__ void edge_sd(const int* __restrict__ ei, int e, int& s_, int& d_) {
  if (e < NE) { s_ = ei[e]; d_ = ei[NE + e]; } else { s_ = d_ = e - NE; }
}

// pass 1: segment max of leaky-relu logits (atomicMax on encoded floats)
template <int H>
__global__ void edge_pass1(const int* __restrict__ ei, const float* __restrict__ al_s,
                           const float* __restrict__ al_d, unsigned* __restrict__ mbuf) {
  int e = blockIdx.x * 256 + threadIdx.x;
  if (e >= NET) return;
  int s_, d_; edge_sd(ei, e, s_, d_);
#pragma unroll
  for (int h = 0; h < H; ++h) {
    float x = al_s[s_ * H + h] + al_d[d_ * H + h];
    x = x > 0.f ? x : SLOPE * x;
    atomicMax(&mbuf[d_ * H + h], fenc(x));
  }
}

// pass 2: segment sum of exp(e - m)
template <int H>
__global__ void edge_pass2(const int* __restrict__ ei, const float* __restrict__ al_s,
                           const float* __restrict__ al_d, const unsigned* __restrict__ mbuf,
                           float* __restrict__ sbuf) {
  int e = blockIdx.x * 256 + threadIdx.x;
  if (e >= NET) return;
  int s_, d_; edge_sd(ei, e, s_, d_);
#pragma unroll
  for (int h = 0; h < H; ++h) {
    float x = al_s[s_ * H + h] + al_d[d_ * H + h];
    x = x > 0.f ? x : SLOPE * x;
    float ex = expf(x - fdec(mbuf[d_ * H + h]));
    atomicAdd(&sbuf[d_ * H + h], ex);
  }
}

// pass 3: out[dst] += h[src] * alpha ; 32 lanes per edge, one channel per head each
template <int H>
__global__ void edge_pass3(const int* __restrict__ ei, const float* __restrict__ Hf,
                           const float* __restrict__ al_s, const float* __restrict__ al_d,
                           const unsigned* __restrict__ mbuf, const float* __restrict__ sbuf,
                           float* __restrict__ outf) {
  constexpr int F = H * 32;
  int lane = threadIdx.x & 31;
  int e = (blockIdx.x * 256 + threadIdx.x) >> 5;
  if (e >= NET) return;
  int s_, d_; edge_sd(ei, e, s_, d_);
#pragma unroll
  for (int h = 0; h < H; ++h) {
    float x = al_s[s_ * H + h] + al_d[d_ * H + h];
    x = x > 0.f ? x : SLOPE * x;
    float alpha = expf(x - fdec(mbuf[d_ * H + h])) / sbuf[d_ * H + h];
    int c = h * 32 + lane;
    atomicAdd(&outf[d_ * F + c], Hf[s_ * F + c] * alpha);
  }
}

template <int F>
__global__ void bias_elu(float* __restrict__ buf, const float* __restrict__ b) {
  const int total = NN * F;
  for (int i = blockIdx.x * blockDim.x + threadIdx.x; i < total;
       i += gridDim.x * blockDim.x) {
    float v = buf[i] + b[i % F];
    buf[i] = v > 0.f ? v : expm1f(v);
  }
}

__global__ void pool_kernel(const float* __restrict__ feat, const int* __restrict__ batch,
                            float* __restrict__ sums, float* __restrict__ cnt) {
  int i = blockIdx.x * 256 + threadIdx.x;
  if (i >= NN * 32) return;
  int n = i >> 5, c = i & 31;
  int g = batch[n];
  atomicAdd(&sums[g * 32 + c], feat[i]);
  if (c == 0) atomicAdd(&cnt[g], 1.0f);
}

__global__ void head_kernel(const float* __restrict__ sums, const float* __restrict__ cnt,
                            const float* __restrict__ Wmu, const float* __restrict__ bmu,
                            const float* __restrict__ Wlv, const float* __restrict__ blv,
                            float* __restrict__ out) {
  int idx = blockIdx.x * 256 + threadIdx.x;
  if (idx >= NG * NLAT) return;
  int g = idx / NLAT, l = idx % NLAT;
  float inv = 1.0f / fmaxf(cnt[g], 1.0f);
  float mu = bmu[l], lv = blv[l];
#pragma unroll
  for (int k = 0; k < 32; ++k) {
    float p = sums[g * 32 + k] * inv;
    mu = fmaf(p, Wmu[k * NLAT + l], mu);
    lv = fmaf(p, Wlv[k * NLAT + l], lv);
  }
  out[g * NLAT + l] = mu;
  out[NG * NLAT + g * NLAT + l] = lv;
}

extern "C" void kernel_launch(void* const* d_in, const int* in_sizes, int n_in,
                              void* d_out, int out_size, void* d_ws, size_t ws_size,
                              hipStream_t stream) {
  const float* x     = (const float*)d_in[0];
  const float* W1    = (const float*)d_in[1];
  const float* as1   = (const float*)d_in[2];
  const float* ad1   = (const float*)d_in[3];
  const float* b1    = (const float*)d_in[4];
  const float* W2    = (const float*)d_in[5];
  const float* as2   = (const float*)d_in[6];
  const float* ad2   = (const float*)d_in[7];
  const float* b2    = (const float*)d_in[8];
  const float* W3    = (const float*)d_in[9];
  const float* as3   = (const float*)d_in[10];
  const float* ad3   = (const float*)d_in[11];
  const float* b3    = (const float*)d_in[12];
  const float* Wmu   = (const float*)d_in[13];
  const float* bmu   = (const float*)d_in[14];
  const float* Wlv   = (const float*)d_in[15];
  const float* blv   = (const float*)d_in[16];
  const int*   ei    = (const int*)d_in[17];
  const int*   batch = (const int*)d_in[18];
  float* out = (float*)d_out;

  float* ws   = (float*)d_ws;
  float* A    = ws;                         // [N,128] h buffer
  float* B    = A + (size_t)NN * 128;       // [N,128] agg/feat buffer
  float* alS  = B + (size_t)NN * 128;       // [N,4]
  float* alD  = alS + (size_t)NN * 4;       // [N,4]
  unsigned* M = (unsigned*)(alD + (size_t)NN * 4);  // [N,4] encoded max
  float* S    = (float*)M + (size_t)NN * 4; // [N,4] exp-sum
  float* sums = S + (size_t)NN * 4;         // [G,32]
  float* cnt  = sums + (size_t)NG * 32;     // [G]

  dim3 blk(256);
  const int EG = (NET + 255) / 256;         // edge grid (thread/edge)
  const int EG32 = (NET + 7) / 8;           // edge grid (32 threads/edge)

  // ---------------- layer 1: x[N,128] -> B[N,128] ----------------
  gemm_k128<128><<<(NN + 7) / 8, blk, 0, stream>>>(x, W1, A);
  attn_coef<128><<<NN / 2, blk, 0, stream>>>(A, as1, ad1, alS, alD);
  hipMemsetAsync(M, 0, (size_t)NN * 4 * sizeof(unsigned), stream);
  hipMemsetAsync(S, 0, (size_t)NN * 4 * sizeof(float), stream);
  hipMemsetAsync(B, 0, (size_t)NN * 128 * sizeof(float), stream);
  edge_pass1<4><<<EG, blk, 0, stream>>>(ei, alS, alD, M);
  edge_pass2<4><<<EG, blk, 0, stream>>>(ei, alS, alD, M, S);
  edge_pass3<4><<<EG32, blk, 0, stream>>>(ei, A, alS, alD, M, S, B);
  bias_elu<128><<<2048, blk, 0, stream>>>(B, b1);

  // ---------------- layer 2: B[N,128] -> B[N,128] ----------------
  gemm_k128<128><<<(NN + 7) / 8, blk, 0, stream>>>(B, W2, A);
  attn_coef<128><<<NN / 2, blk, 0, stream>>>(A, as2, ad2, alS, alD);
  hipMemsetAsync(M, 0, (size_t)NN * 4 * sizeof(unsigned), stream);
  hipMemsetAsync(S, 0, (size_t)NN * 4 * sizeof(float), stream);
  hipMemsetAsync(B, 0, (size_t)NN * 128 * sizeof(float), stream);  // B dead after gemm
  edge_pass1<4><<<EG, blk, 0, stream>>>(ei, alS, alD, M);
  edge_pass2<4><<<EG, blk, 0, stream>>>(ei, alS, alD, M, S);
  edge_pass3<4><<<EG32, blk, 0, stream>>>(ei, A, alS, alD, M, S, B);
  bias_elu<128><<<2048, blk, 0, stream>>>(B, b2);

  // ---------------- layer 3: B[N,128] -> B[N,32] (H=1) ----------------
  gemm_k128<32><<<(NN + 31) / 32, blk, 0, stream>>>(B, W3, A);   // A used as [N,32]
  attn_coef<32><<<NN / 8, blk, 0, stream>>>(A, as3, ad3, alS, alD);
  hipMemsetAsync(M, 0, (size_t)NN * sizeof(unsigned), stream);
  hipMemsetAsync(S, 0, (size_t)NN * sizeof(float), stream);
  hipMemsetAsync(B, 0, (size_t)NN * 32 * sizeof(float), stream);  // B dead after gemm
  edge_pass1<1><<<EG, blk, 0, stream>>>(ei, alS, alD, M);
  edge_pass2<1><<<EG, blk, 0, stream>>>(ei, alS, alD, M, S);
  edge_pass3<1><<<EG32, blk, 0, stream>>>(ei, A, alS, alD, M, S, B);
  bias_elu<32><<<2048, blk, 0, stream>>>(B, b3);

  // ---------------- pool + heads ----------------
  hipMemsetAsync(sums, 0, (size_t)NG * 32 * sizeof(float), stream);
  hipMemsetAsync(cnt, 0, (size_t)NG * sizeof(float), stream);
  pool_kernel<<<(NN * 32) / 256, blk, 0, stream>>>(B, batch, sums, cnt);
  head_kernel<<<(NG * NLAT + 255) / 256, blk, 0, stream>>>(sums, cnt, Wmu, bmu, Wlv, blv, out);
}

// Round 2
// 516.316 us; speedup vs baseline: 3.3474x; 3.3474x over previous
//
#include <hip/hip_runtime.h>

// Problem constants (from reference)
constexpr int NN   = 50000;            // nodes
constexpr int NE   = 800000;           // edges (before self-loops)
constexpr int NET  = NE + NN;          // edges incl. self-loops
constexpr int NG   = 512;              // graphs
constexpr int NLAT = 64;               // latent dim
constexpr float SLOPE = 0.2f;          // leaky relu slope

__device__ __forceinline__ void edge_sd(const int* __restrict__ ei, int e, int& s_, int& d_) {
  if (e < NE) { s_ = ei[e]; d_ = ei[NE + e]; } else { s_ = d_ = e - NE; }
}

// ======================= CSR build (per launch, reused by 3 layers) =======================
__global__ void hist_kernel(const int* __restrict__ ei, int* __restrict__ deg) {
  int e = blockIdx.x * 256 + threadIdx.x;
  if (e >= NET) return;
  int s_, d_; edge_sd(ei, e, s_, d_);
  atomicAdd(&deg[d_], 1);
}

__global__ void scan_a(const int* __restrict__ deg, int* __restrict__ incl,
                       int* __restrict__ bsum) {
  __shared__ int tmp[256];
  int i = blockIdx.x * 256 + threadIdx.x;
  int v = (i < NN) ? deg[i] : 0;
  tmp[threadIdx.x] = v;
  __syncthreads();
  for (int off = 1; off < 256; off <<= 1) {
    int t = (threadIdx.x >= off) ? tmp[threadIdx.x - off] : 0;
    __syncthreads();
    tmp[threadIdx.x] += t;
    __syncthreads();
  }
  if (i < NN) incl[i] = tmp[threadIdx.x];
  if (threadIdx.x == 255) bsum[blockIdx.x] = tmp[255];
}

__global__ void scan_b(int* __restrict__ bsum, int nb) {  // single block
  __shared__ int tmp[256];
  int v = (threadIdx.x < nb) ? bsum[threadIdx.x] : 0;
  tmp[threadIdx.x] = v;
  __syncthreads();
  for (int off = 1; off < 256; off <<= 1) {
    int t = (threadIdx.x >= off) ? tmp[threadIdx.x - off] : 0;
    __syncthreads();
    tmp[threadIdx.x] += t;
    __syncthreads();
  }
  if (threadIdx.x < nb) bsum[threadIdx.x] = tmp[threadIdx.x];
}

__global__ void scan_c(const int* __restrict__ incl, const int* __restrict__ bsum,
                       const int* __restrict__ deg, int* __restrict__ row_ptr,
                       int* __restrict__ cursor) {
  int i = blockIdx.x * 256 + threadIdx.x;
  if (i >= NN) return;
  int off = blockIdx.x ? bsum[blockIdx.x - 1] : 0;
  int inc = incl[i] + off;
  row_ptr[i + 1] = inc;
  cursor[i] = inc - deg[i];
  if (i == 0) row_ptr[0] = 0;
}

__global__ void scatter_kernel(const int* __restrict__ ei, int* __restrict__ cursor,
                               int* __restrict__ ssrc) {
  int e = blockIdx.x * 256 + threadIdx.x;
  if (e >= NET) return;
  int s_, d_; edge_sd(ei, e, s_, d_);
  int pos = atomicAdd(&cursor[d_], 1);
  ssrc[pos] = s_;
}

// ======================= GEMM: C[n,j] = sum_k X[n,k] W[k,j], K=128 =======================
template <int CN>
__global__ void gemm_k128(const float* __restrict__ X, const float* __restrict__ W,
                          float* __restrict__ Hout) {
  constexpr int RPI = 256 / CN;
  constexpr int R   = RPI * 4;
  __shared__ float xs[R][128];
  const int col  = threadIdx.x % CN;
  const int rsub = threadIdx.x / CN;
  const int row0 = blockIdx.x * R;
  for (int i = threadIdx.x; i < R * 128; i += 256) {
    int r = i >> 7, k = i & 127;
    int gr = row0 + r;
    xs[r][k] = (gr < NN) ? X[gr * 128 + k] : 0.0f;
  }
  __syncthreads();
  float acc[4] = {0.f, 0.f, 0.f, 0.f};
  for (int k = 0; k < 128; ++k) {
    float w = W[k * CN + col];
#pragma unroll
    for (int rr = 0; rr < 4; ++rr)
      acc[rr] = fmaf(xs[rsub + rr * RPI][k], w, acc[rr]);
  }
#pragma unroll
  for (int rr = 0; rr < 4; ++rr) {
    int gr = row0 + rsub + rr * RPI;
    if (gr < NN) Hout[gr * CN + col] = acc[rr];
  }
}

// ======================= per-node attention coefficients =======================
template <int F>
__global__ void attn_coef(const float* __restrict__ Hf, const float* __restrict__ a_s,
                          const float* __restrict__ a_d, float* __restrict__ al_s,
                          float* __restrict__ al_d) {
  const int t = threadIdx.x % F;
  const int node = blockIdx.x * (256 / F) + threadIdx.x / F;
  if (node >= NN) return;
  float v  = Hf[node * F + t];
  float ps = v * a_s[t];
  float pd = v * a_d[t];
#pragma unroll
  for (int off = 16; off >= 1; off >>= 1) {
    ps += __shfl_xor(ps, off, 64);
    pd += __shfl_xor(pd, off, 64);
  }
  if ((t & 31) == 0) {
    al_s[node * (F / 32) + (t >> 5)] = ps;
    al_d[node * (F / 32) + (t >> 5)] = pd;
  }
}

// ============ deterministic per-node softmax stats (16 lanes per node, online) ============
template <int H>
__global__ void seg_stats(const int* __restrict__ rp, const int* __restrict__ ssrc,
                          const float* __restrict__ alS, const float* __restrict__ alD,
                          float* __restrict__ mb, float* __restrict__ isb) {
  int idx = blockIdx.x * 256 + threadIdx.x;
  int node = idx >> 4;
  int sl = idx & 15;
  if (node >= NN) return;
  int beg = rp[node], end = rp[node + 1];
  float ad[H], mx[H], sm[H];
#pragma unroll
  for (int h = 0; h < H; ++h) { ad[h] = alD[node * H + h]; mx[h] = -1e30f; sm[h] = 0.f; }
  for (int e = beg + sl; e < end; e += 16) {
    int s = ssrc[e];
#pragma unroll
    for (int h = 0; h < H; ++h) {
      float x = alS[s * H + h] + ad[h];
      x = x > 0.f ? x : SLOPE * x;
      float nm = fmaxf(mx[h], x);
      sm[h] = sm[h] * __expf(mx[h] - nm) + __expf(x - nm);
      mx[h] = nm;
    }
  }
#pragma unroll
  for (int off = 8; off >= 1; off >>= 1) {
#pragma unroll
    for (int h = 0; h < H; ++h) {
      float om = __shfl_xor(mx[h], off, 64);
      float os = __shfl_xor(sm[h], off, 64);
      float nm = fmaxf(mx[h], om);
      sm[h] = sm[h] * __expf(mx[h] - nm) + os * __expf(om - nm);
      mx[h] = nm;
    }
  }
  if (sl == 0) {
#pragma unroll
    for (int h = 0; h < H; ++h) {
      mb[node * H + h] = mx[h];
      isb[node * H + h] = 1.0f / sm[h];
    }
  }
}

// ============ aggregation, H=4 (F=128): one wave per node, chunk 16 edges ============
__global__ void seg_agg_h4(const int* __restrict__ rp, const int* __restrict__ ssrc,
                           const float* __restrict__ Hf, const float* __restrict__ alS,
                           const float* __restrict__ alD, const float* __restrict__ mb,
                           const float* __restrict__ isb, const float* __restrict__ bias,
                           float* __restrict__ outf) {
  int node = (blockIdx.x * 256 + threadIdx.x) >> 6;
  int lane = threadIdx.x & 63;
  if (node >= NN) return;
  int beg = rp[node], end = rp[node + 1];
  int el = lane & 15, hh = lane >> 4;            // alpha-phase mapping: (edge el, head hh)
  float ad_h = alD[node * 4 + hh];
  float m_h  = mb[node * 4 + hh];
  float is_h = isb[node * 4 + hh];
  int h0 = lane >> 5;                            // head of channel c0 = lane
  float acc0 = 0.f, acc1 = 0.f;
  for (int ch = beg; ch < end; ch += 16) {
    int cnt = min(16, end - ch);
    int sv = 0; float av = 0.f;
    if (el < cnt) {
      sv = ssrc[ch + el];
      float x = alS[sv * 4 + hh] + ad_h;
      x = x > 0.f ? x : SLOPE * x;
      av = __expf(x - m_h) * is_h;
    }
    for (int e2 = 0; e2 < cnt; ++e2) {
      int   s  = __shfl(sv, e2, 64);             // lane e2 holds (el=e2, hh=0)
      float a0 = __shfl(av, h0 * 16 + e2, 64);
      float a1 = __shfl(av, (h0 + 2) * 16 + e2, 64);
      acc0 = fmaf(Hf[s * 128 + lane],      a0, acc0);
      acc1 = fmaf(Hf[s * 128 + 64 + lane], a1, acc1);
    }
  }
  float v0 = acc0 + bias[lane];
  float v1 = acc1 + bias[64 + lane];
  outf[node * 128 + lane]      = v0 > 0.f ? v0 : expm1f(v0);
  outf[node * 128 + 64 + lane] = v1 > 0.f ? v1 : expm1f(v1);
}

// ============ aggregation, H=1 (F=32): half-wave per node, chunk 32 edges ============
__global__ void seg_agg_h1(const int* __restrict__ rp, const int* __restrict__ ssrc,
                           const float* __restrict__ Hf, const float* __restrict__ alS,
                           const float* __restrict__ alD, const float* __restrict__ mb,
                           const float* __restrict__ isb, const float* __restrict__ bias,
                           float* __restrict__ outf) {
  int node = (blockIdx.x * 256 + threadIdx.x) >> 5;
  int lane = threadIdx.x & 31;
  if (node >= NN) return;
  int beg = rp[node], end = rp[node + 1];
  float ad = alD[node], m_ = mb[node], is_ = isb[node];
  float acc = 0.f;
  for (int ch = beg; ch < end; ch += 32) {
    int cnt = min(32, end - ch);
    int sv = 0; float av = 0.f;
    if (lane < cnt) {
      sv = ssrc[ch + lane];
      float x = alS[sv] + ad;
      x = x > 0.f ? x : SLOPE * x;
      av = __expf(x - m_) * is_;
    }
    for (int e2 = 0; e2 < cnt; ++e2) {
      int   s = __shfl(sv, e2, 32);
      float a = __shfl(av, e2, 32);
      acc = fmaf(Hf[s * 32 + lane], a, acc);
    }
  }
  float v = acc + bias[lane];
  outf[node * 32 + lane] = v > 0.f ? v : expm1f(v);
}

// ======================= pool + heads =======================
__global__ void pool_kernel(const float* __restrict__ feat, const int* __restrict__ batch,
                            float* __restrict__ sums, float* __restrict__ cnt) {
  int i = blockIdx.x * 256 + threadIdx.x;
  if (i >= NN * 32) return;
  int n = i >> 5, c = i & 31;
  int g = batch[n];
  atomicAdd(&sums[g * 32 + c], feat[i]);
  if (c == 0) atomicAdd(&cnt[g], 1.0f);
}

__global__ void head_kernel(const float* __restrict__ sums, const float* __restrict__ cnt,
                            const float* __restrict__ Wmu, const float* __restrict__ bmu,
                            const float* __restrict__ Wlv, const float* __restrict__ blv,
                            float* __restrict__ out) {
  int idx = blockIdx.x * 256 + threadIdx.x;
  if (idx >= NG * NLAT) return;
  int g = idx / NLAT, l = idx % NLAT;
  float inv = 1.0f / fmaxf(cnt[g], 1.0f);
  float mu = bmu[l], lv = blv[l];
#pragma unroll
  for (int k = 0; k < 32; ++k) {
    float p = sums[g * 32 + k] * inv;
    mu = fmaf(p, Wmu[k * NLAT + l], mu);
    lv = fmaf(p, Wlv[k * NLAT + l], lv);
  }
  out[g * NLAT + l] = mu;
  out[NG * NLAT + g * NLAT + l] = lv;
}

extern "C" void kernel_launch(void* const* d_in, const int* in_sizes, int n_in,
                              void* d_out, int out_size, void* d_ws, size_t ws_size,
                              hipStream_t stream) {
  const float* x     = (const float*)d_in[0];
  const float* W1    = (const float*)d_in[1];
  const float* as1   = (const float*)d_in[2];
  const float* ad1   = (const float*)d_in[3];
  const float* b1    = (const float*)d_in[4];
  const float* W2    = (const float*)d_in[5];
  const float* as2   = (const float*)d_in[6];
  const float* ad2   = (const float*)d_in[7];
  const float* b2    = (const float*)d_in[8];
  const float* W3    = (const float*)d_in[9];
  const float* as3   = (const float*)d_in[10];
  const float* ad3   = (const float*)d_in[11];
  const float* b3    = (const float*)d_in[12];
  const float* Wmu   = (const float*)d_in[13];
  const float* bmu   = (const float*)d_in[14];
  const float* Wlv   = (const float*)d_in[15];
  const float* blv   = (const float*)d_in[16];
  const int*   ei    = (const int*)d_in[17];
  const int*   batch = (const int*)d_in[18];
  float* out = (float*)d_out;

  float* ws   = (float*)d_ws;
  float* A    = ws;                          // [N,128] GEMM output (h)
  float* B    = A + (size_t)NN * 128;        // [N,128] agg/feature buffer
  float* alS  = B + (size_t)NN * 128;        // [N,4]
  float* alD  = alS + (size_t)NN * 4;        // [N,4]
  float* M    = alD + (size_t)NN * 4;        // [N,4] softmax max
  float* IS   = M + (size_t)NN * 4;          // [N,4] 1/denominator
  float* sums = IS + (size_t)NN * 4;         // [G,32]
  float* cnt  = sums + (size_t)NG * 32;      // [G]
  int* deg    = (int*)(cnt + NG);            // [N]
  int* rp     = deg + NN;                    // [N+1]
  int* cursor = rp + NN + 1;                 // [N]
  int* incl   = cursor + NN;                 // [N]
  int* bsum   = incl + NN;                   // [256]
  int* ssrc   = bsum + 256;                  // [NET] dst-sorted src indices

  dim3 blk(256);
  const int EG = (NET + 255) / 256;
  const int SCB = (NN + 255) / 256;          // scan blocks (196)

  // ---------------- CSR build (topology shared by all 3 layers) ----------------
  hipMemsetAsync(deg, 0, (size_t)NN * sizeof(int), stream);
  hist_kernel<<<EG, blk, 0, stream>>>(ei, deg);
  scan_a<<<SCB, blk, 0, stream>>>(deg, incl, bsum);
  scan_b<<<1, blk, 0, stream>>>(bsum, SCB);
  scan_c<<<SCB, blk, 0, stream>>>(incl, bsum, deg, rp, cursor);
  scatter_kernel<<<EG, blk, 0, stream>>>(ei, cursor, ssrc);

  // ---------------- layer 1: x[N,128] -> B[N,128] ----------------
  gemm_k128<128><<<(NN + 7) / 8, blk, 0, stream>>>(x, W1, A);
  attn_coef<128><<<NN / 2, blk, 0, stream>>>(A, as1, ad1, alS, alD);
  seg_stats<4><<<(NN * 16) / 256, blk, 0, stream>>>(rp, ssrc, alS, alD, M, IS);
  seg_agg_h4<<<(NN * 64) / 256, blk, 0, stream>>>(rp, ssrc, A, alS, alD, M, IS, b1, B);

  // ---------------- layer 2: B[N,128] -> B[N,128] ----------------
  gemm_k128<128><<<(NN + 7) / 8, blk, 0, stream>>>(B, W2, A);
  attn_coef<128><<<NN / 2, blk, 0, stream>>>(A, as2, ad2, alS, alD);
  seg_stats<4><<<(NN * 16) / 256, blk, 0, stream>>>(rp, ssrc, alS, alD, M, IS);
  seg_agg_h4<<<(NN * 64) / 256, blk, 0, stream>>>(rp, ssrc, A, alS, alD, M, IS, b2, B);

  // ---------------- layer 3: B[N,128] -> B[N,32] ----------------
  gemm_k128<32><<<(NN + 31) / 32, blk, 0, stream>>>(B, W3, A);   // A as [N,32]
  attn_coef<32><<<NN / 8, blk, 0, stream>>>(A, as3, ad3, alS, alD);
  seg_stats<1><<<(NN * 16) / 256, blk, 0, stream>>>(rp, ssrc, alS, alD, M, IS);
  seg_agg_h1<<<(NN * 32) / 256, blk, 0, stream>>>(rp, ssrc, A, alS, alD, M, IS, b3, B);

  // ---------------- pool + heads ----------------
  hipMemsetAsync(sums, 0, (size_t)NG * 32 * sizeof(float), stream);
  hipMemsetAsync(cnt, 0, (size_t)NG * sizeof(float), stream);
  pool_kernel<<<(NN * 32) / 256, blk, 0, stream>>>(B, batch, sums, cnt);
  head_kernel<<<(NG * NLAT + 255) / 256, blk, 0, stream>>>(sums, cnt, Wmu, bmu, Wlv, blv, out);
}